// Round 7
// baseline (618.066 us; speedup 1.0000x reference)
//
#include <hip/hip_runtime.h>
#include <hip/hip_bf16.h>

#define ALPHA_ 0.2f
#define EPS_ 1e-12f

typedef short short8 __attribute__((ext_vector_type(8)));
typedef unsigned short ushort4v __attribute__((ext_vector_type(4)));
typedef float f32x4 __attribute__((ext_vector_type(4)));

constexpr int BB = 16, KK = 16, DD = 256, NNEG = 16384;
constexpr int ITERS = 5;   // Newton-Schulz iterations (odd => final lands in XB)

// ---- workspace layout (float offsets) ---- total 5,309,440 floats (proven size)
constexpr size_t OFF_NL    = 0;         // 2M floats: neg-lo (overlays XA after Newton)
constexpr size_t OFF_XA_H  = 1048576;
constexpr size_t OFF_XA_L  = 1572864;
constexpr size_t OFF_XB_H  = 2097152;   // FINAL A hi
constexpr size_t OFF_XB_L  = 2621440;   // FINAL A lo
constexpr size_t OFF_NH    = 3145728;   // 2M floats: neg-hi (overlays T+S after Newton)
constexpr size_t OFF_T_H   = 3145728;
constexpr size_t OFF_CS    = 3145728;   // colsum[16][256] (overlays T_H during prep)
constexpr size_t OFF_C01   = 3149824;   // c0[16], c1[16]
constexpr size_t OFF_T_L   = 3670016;
constexpr size_t OFF_S_H   = 4194304;
constexpr size_t OFF_S_L   = 4718592;
constexpr size_t OFF_PA_H  = 5242880;   // 65536 ushorts
constexpr size_t OFF_PA_L  = 5275648;
constexpr size_t OFF_PAP   = 5308416;
constexpr size_t OFF_DPOS2 = 5308672;
constexpr size_t OFF_MINA  = 5308928;
constexpr size_t OFF_MINV  = 5309184;

// ---------- bf16 split helpers (RNE) ----------
__device__ inline unsigned short bf_hi(float x) {
    unsigned u = __float_as_uint(x);
    return (unsigned short)((u + 0x7fffu + ((u >> 16) & 1u)) >> 16);
}
__device__ inline float bf_tof(unsigned short h) { return __uint_as_float(((unsigned)h) << 16); }
__device__ inline void split2(float x, unsigned short& h, unsigned short& l) {
    h = bf_hi(x); l = bf_hi(x - bf_tof(h));
}

// ---------- prep 1: column abs-sums (Gershgorin), 256 blocks ----------
__global__ __launch_bounds__(256) void kcolsum(const float* __restrict__ Sig, float* __restrict__ cs) {
    int b = blockIdx.x >> 4, cg = blockIdx.x & 15;
    int t = threadIdx.x, tx = t & 15, rg = t >> 4;
    const float* S = Sig + (size_t)b * 65536;
    int col = cg * 16 + tx;
    float s = 0.f;
    #pragma unroll 4
    for (int i = rg * 16; i < rg * 16 + 16; ++i) s += fabsf(S[(size_t)i * 256 + col]);
    __shared__ float red[256];
    red[rg * 16 + tx] = s; __syncthreads();
    if (rg == 0) {
        float tot = 0.f;
        #pragma unroll
        for (int y = 0; y < 16; ++y) tot += red[y * 16 + tx];
        cs[b * 256 + col] = tot;
    }
}

// ---------- prep 2: G = max colsum -> degree-2 init coefficients ----------
__global__ __launch_bounds__(256) void kcoef(const float* __restrict__ cs, float* __restrict__ c01) {
    int t = threadIdx.x, b = t >> 4, ch = t & 15;
    float m = 0.f;
    #pragma unroll
    for (int i = 0; i < 16; ++i) m = fmaxf(m, cs[b * 256 + ch * 16 + i]);
    __shared__ float red[256];
    red[t] = m; __syncthreads();
    if (ch == 0) {
        float G = red[b * 16];
        #pragma unroll
        for (int y = 1; y < 16; ++y) G = fmaxf(G, red[b * 16 + y]);
        float c1 = -2.f / (G + (G + 1.f) * (G + 1.f) * 0.25f);
        c01[b] = -c1 * (G + 1.f); c01[16 + b] = c1;
    }
}

// ---------- prep 3: split S and X0 = c0*I + c1*S (4096 blocks, coalesced) ----------
__global__ __launch_bounds__(256) void kinit(const float* __restrict__ Sig, float* __restrict__ ws,
                                             const float* __restrict__ c01) {
    int idx = blockIdx.x * 256 + threadIdx.x;
    int b = idx >> 16, rc = idx & 65535;
    int r = rc >> 8, c = rc & 255;
    float v = Sig[idx];
    unsigned short h, l;
    split2(v, h, l);
    ((unsigned short*)(ws + OFF_S_H))[idx] = h; ((unsigned short*)(ws + OFF_S_L))[idx] = l;
    float x0 = c01[16 + b] * v + ((r == c) ? c01[b] : 0.f);
    split2(x0, h, l);
    ((unsigned short*)(ws + OFF_XA_H))[idx] = h; ((unsigned short*)(ws + OFF_XA_L))[idx] = l;
}

// ---------- batched 256x256 MFMA split GEMM, 32x64 tiles, 512 blocks ----------
__global__ __launch_bounds__(256) void gemm_mfma(const unsigned short* __restrict__ Ah,
                                                 const unsigned short* __restrict__ Al,
                                                 const unsigned short* __restrict__ Bh,
                                                 const unsigned short* __restrict__ Bl,
                                                 unsigned short* __restrict__ Ch,
                                                 unsigned short* __restrict__ Cl, int mode2i) {
    int b = blockIdx.y;
    int i0 = (blockIdx.x >> 2) * 32, j0 = (blockIdx.x & 3) * 64;
    size_t base = (size_t)b * 65536;
    int t = threadIdx.x, lane = t & 63, w = t >> 6;
    int l15 = lane & 15, lg = lane >> 4;
    f32x4 acc[2] = {};
    int ar0 = i0 + l15;
    int br  = j0 + w * 16 + l15;
    #pragma unroll
    for (int e0 = 0; e0 < 256; e0 += 32) {
        int eo = e0 + 8 * lg;
        short8 a_h[2], a_l[2];
        #pragma unroll
        for (int m = 0; m < 2; ++m) {
            size_t off = base + (size_t)(ar0 + m * 16) * 256 + eo;
            a_h[m] = *reinterpret_cast<const short8*>(Ah + off);
            a_l[m] = *reinterpret_cast<const short8*>(Al + off);
        }
        size_t boff = base + (size_t)br * 256 + eo;     // symmetric: row == col
        short8 b_h = *reinterpret_cast<const short8*>(Bh + boff);
        short8 b_l = *reinterpret_cast<const short8*>(Bl + boff);
        #pragma unroll
        for (int m = 0; m < 2; ++m) {
            acc[m] = __builtin_amdgcn_mfma_f32_16x16x32_bf16(a_h[m], b_h, acc[m], 0, 0, 0);
            acc[m] = __builtin_amdgcn_mfma_f32_16x16x32_bf16(a_h[m], b_l, acc[m], 0, 0, 0);
            acc[m] = __builtin_amdgcn_mfma_f32_16x16x32_bf16(a_l[m], b_h, acc[m], 0, 0, 0);
        }
    }
    #pragma unroll
    for (int m = 0; m < 2; ++m)
        #pragma unroll
        for (int r = 0; r < 4; ++r) {
            int row = i0 + m * 16 + 4 * lg + r;
            int col = j0 + w * 16 + l15;
            float v = acc[m][r];
            if (mode2i) v = ((row == col) ? 2.f : 0.f) - v;
            unsigned short h, l; split2(v, h, l);
            size_t off = base + (size_t)row * 256 + col;
            Ch[off] = h; Cl[off] = l;
        }
}

// ---------- negatives pre-split (once) + min-buffer init ----------
__global__ __launch_bounds__(256) void knegsplit(const float* __restrict__ negs,
                                                 unsigned short* __restrict__ NH,
                                                 unsigned short* __restrict__ NL,
                                                 unsigned* __restrict__ mina,
                                                 unsigned* __restrict__ minv) {
    size_t i8 = ((size_t)blockIdx.x * 256 + threadIdx.x) * 8;
    f32x4 v0 = *reinterpret_cast<const f32x4*>(negs + i8);
    f32x4 v1 = *reinterpret_cast<const f32x4*>(negs + i8 + 4);
    short8 h, l;
    #pragma unroll
    for (int j = 0; j < 4; ++j) {
        unsigned short hh, ll;
        split2(v0[j], hh, ll); h[j] = (short)hh; l[j] = (short)ll;
        split2(v1[j], hh, ll); h[4 + j] = (short)hh; l[4 + j] = (short)ll;
    }
    *reinterpret_cast<short8*>(NH + i8) = h;
    *reinterpret_cast<short8*>(NL + i8) = l;
    if (blockIdx.x == 0) {
        mina[threadIdx.x] = 0x7f800000u; minv[threadIdx.x] = 0x7f800000u;
    }
}

// ---------- per (b,k): PA row (split), pAp, dpos2 ----------
__global__ __launch_bounds__(256) void k2(const float* __restrict__ Z1, const float* __restrict__ Z2,
                                          const int* __restrict__ match,
                                          const unsigned short* __restrict__ AH,
                                          const unsigned short* __restrict__ AL,
                                          float* __restrict__ ws) {
    int bk = blockIdx.x; int b = bk >> 4; int t = threadIdx.x;
    const unsigned short* Ah = AH + (size_t)b * 65536;
    const unsigned short* Al = AL + (size_t)b * 65536;
    __shared__ float z[DD], df[DD];
    __shared__ float red[256];
    int m = match[bk];
    float zv = Z1[(size_t)bk * DD + t];
    float qv = Z2[((size_t)b * KK + m) * DD + t];
    z[t] = zv; df[t] = zv - qv;
    __syncthreads();
    float pa = 0.f, da = 0.f;
    for (int e = 0; e < DD; ++e) {
        float Ae = bf_tof(Ah[(size_t)e * 256 + t]) + bf_tof(Al[(size_t)e * 256 + t]);
        pa = fmaf(z[e], Ae, pa);
        da = fmaf(df[e], Ae, da);
    }
    unsigned short ph, pl; split2(pa, ph, pl);
    ((unsigned short*)(ws + OFF_PA_H))[(size_t)bk * 256 + t] = ph;
    ((unsigned short*)(ws + OFF_PA_L))[(size_t)bk * 256 + t] = pl;
    float dfv = df[t];
    red[t] = pa * zv; __syncthreads();
    for (int s = 128; s > 0; s >>= 1) { if (t < s) red[t] += red[t + s]; __syncthreads(); }
    float pAp = red[0]; __syncthreads();
    red[t] = da * dfv; __syncthreads();
    for (int s = 128; s > 0; s >>= 1) { if (t < s) red[t] += red[t + s]; __syncthreads(); }
    if (t == 0) {
        ws[OFF_PAP + bk]   = pAp;
        ws[OFF_DPOS2 + bk] = fmaxf(red[0], EPS_);
    }
}

// ---------- main kernel: role-swapped, LDS dbuf negatives, 1 barrier/chunk ----------
// C[f,n] = A-rows (global, L2-hot) x N-rows (LDS). 512 thr = 8 waves, wf = wid.
// Wave wf: f-tiles {wf, wf+8}; all 8 n-tiles. PA: wf0 j0-3, wf1 j4-7.
__global__ __launch_bounds__(512, 4) void k3(const unsigned short* __restrict__ Ahi,
                                             const unsigned short* __restrict__ Alo,
                                             const unsigned short* __restrict__ PAh,
                                             const unsigned short* __restrict__ PAl,
                                             const unsigned short* __restrict__ NH,
                                             const unsigned short* __restrict__ NL,
                                             const float* __restrict__ pap,
                                             const float* __restrict__ dpos2,
                                             unsigned* __restrict__ mina,
                                             unsigned* __restrict__ minv) {
    __shared__ float smem[10240];                      // 40 KB: 2 x dbuf [128][40] x {h,l}
    unsigned short* BH0 = (unsigned short*)smem;
    unsigned short* BL0 = BH0 + 5120;
    unsigned short* BH1 = BL0 + 5120;
    unsigned short* BL1 = BH1 + 5120;

    int lin = blockIdx.x;
    int x  = lin & 7;
    int q  = lin >> 3;
    int b  = q >> 4;
    int n0 = (x * 16 + (q & 15)) * 128;                // XCD-local negative slice
    int t = threadIdx.x, lane = t & 63, wf = t >> 6;
    int l15 = lane & 15, lg = lane >> 4;
    const unsigned short* Ab  = Ahi + (size_t)b * 65536;
    const unsigned short* Al_ = Alo + (size_t)b * 65536;
    const unsigned short* Ph  = PAh + (size_t)b * 4096;
    const unsigned short* Pl  = PAl + (size_t)b * 4096;
    const unsigned short* Nh  = NH + (size_t)n0 * 256;
    const unsigned short* Nl  = NL + (size_t)n0 * 256;

    int srow = t >> 2, sq = t & 3;                     // staging: neg row, 16B quarter
    const unsigned short* NhS = Nh + (size_t)srow * 256 + sq * 8;
    const unsigned short* NlS = Nl + (size_t)srow * 256 + sq * 8;
    int soff = srow * 40 + sq * 8;

    // A-row fragment base pointers (fixed per thread; e-window advances by c*32)
    const unsigned short* a0h = Ab  + (size_t)(wf * 16 + l15) * 256 + 8 * lg;
    const unsigned short* a0l = Al_ + (size_t)(wf * 16 + l15) * 256 + 8 * lg;
    const unsigned short* a1h = Ab  + (size_t)((wf + 8) * 16 + l15) * 256 + 8 * lg;
    const unsigned short* a1l = Al_ + (size_t)((wf + 8) * 16 + l15) * 256 + 8 * lg;
    const unsigned short* pph = Ph + (size_t)l15 * 256 + 8 * lg;
    const unsigned short* ppl = Pl + (size_t)l15 * 256 + 8 * lg;

    f32x4 acc[2][8] = {};
    f32x4 accp[4] = {};

    // prologue: stage chunk 0 into buf0
    short8 sH = *reinterpret_cast<const short8*>(NhS);
    short8 sL = *reinterpret_cast<const short8*>(NlS);
    *reinterpret_cast<short8*>(BH0 + soff) = sH;
    *reinterpret_cast<short8*>(BL0 + soff) = sL;
    __syncthreads();

    #pragma unroll
    for (int c = 0; c < 8; ++c) {
        unsigned short* cH = (c & 1) ? BH1 : BH0;
        unsigned short* cL = (c & 1) ? BL1 : BL0;
        unsigned short* nH = (c & 1) ? BH0 : BH1;
        unsigned short* nL = (c & 1) ? BL0 : BL1;
        if (c < 7) {                                    // stage loads for c+1 (regs)
            sH = *reinterpret_cast<const short8*>(NhS + (c + 1) * 32);
            sL = *reinterpret_cast<const short8*>(NlS + (c + 1) * 32);
        }
        #pragma unroll
        for (int i = 0; i < 2; ++i) {
            short8 ah = *reinterpret_cast<const short8*>((i ? a1h : a0h) + c * 32);
            short8 al = *reinterpret_cast<const short8*>((i ? a1l : a0l) + c * 32);
            #pragma unroll
            for (int j = 0; j < 8; ++j) {
                short8 bh = *reinterpret_cast<const short8*>(cH + (j * 16 + l15) * 40 + 8 * lg);
                short8 bl = *reinterpret_cast<const short8*>(cL + (j * 16 + l15) * 40 + 8 * lg);
                acc[i][j] = __builtin_amdgcn_mfma_f32_16x16x32_bf16(ah, bh, acc[i][j], 0, 0, 0);
                acc[i][j] = __builtin_amdgcn_mfma_f32_16x16x32_bf16(ah, bl, acc[i][j], 0, 0, 0);
                acc[i][j] = __builtin_amdgcn_mfma_f32_16x16x32_bf16(al, bh, acc[i][j], 0, 0, 0);
            }
        }
        if (wf < 2) {                                   // PA tile, half the n-range each
            short8 ph = *reinterpret_cast<const short8*>(pph + c * 32);
            short8 pl = *reinterpret_cast<const short8*>(ppl + c * 32);
            #pragma unroll
            for (int jj = 0; jj < 4; ++jj) {
                int j = wf * 4 + jj;
                short8 bh = *reinterpret_cast<const short8*>(cH + (j * 16 + l15) * 40 + 8 * lg);
                short8 bl = *reinterpret_cast<const short8*>(cL + (j * 16 + l15) * 40 + 8 * lg);
                accp[jj] = __builtin_amdgcn_mfma_f32_16x16x32_bf16(ph, bh, accp[jj], 0, 0, 0);
                accp[jj] = __builtin_amdgcn_mfma_f32_16x16x32_bf16(ph, bl, accp[jj], 0, 0, 0);
                accp[jj] = __builtin_amdgcn_mfma_f32_16x16x32_bf16(pl, bh, accp[jj], 0, 0, 0);
            }
        }
        if (c < 7) {                                    // write next buffer (no race: != cur)
            *reinterpret_cast<short8*>(nH + soff) = sH;
            *reinterpret_cast<short8*>(nL + soff) = sL;
        }
        __syncthreads();                                // single barrier per chunk
    }

    // ---- epilogue (smem reused; last barrier above fences the dbuf reads) ----
    float* pAn_l = smem;            // [128][17]
    float* nAnp  = smem + 2176;     // [8][128]
    float* nAn_l = smem + 3200;     // [128]
    float* reda  = smem + 3328;     // [512]
    float* redv  = smem + 3840;     // [512]

    if (wf < 2) {
        #pragma unroll
        for (int jj = 0; jj < 4; ++jj) {
            int n = (wf * 4 + jj) * 16 + l15;
            #pragma unroll
            for (int r = 0; r < 4; ++r)
                pAn_l[n * 17 + 4 * lg + r] = accp[jj][r];   // pAn[n][k], k=4lg+r
        }
    }
    #pragma unroll
    for (int j = 0; j < 8; ++j) {
        int n = j * 16 + l15;
        float p = 0.f;
        #pragma unroll
        for (int i = 0; i < 2; ++i) {
            int fb = (wf + 8 * i) * 16 + 4 * lg;
            ushort4v wh = *reinterpret_cast<const ushort4v*>(NH + (size_t)(n0 + n) * 256 + fb);
            ushort4v wl = *reinterpret_cast<const ushort4v*>(NL + (size_t)(n0 + n) * 256 + fb);
            #pragma unroll
            for (int r = 0; r < 4; ++r) {
                float w = bf_tof(wh[r]) + bf_tof(wl[r]);
                p = fmaf(acc[i][j][r], w, p);
            }
        }
        p += __shfl_xor(p, 16);                         // reduce over lg (f-rows)
        p += __shfl_xor(p, 32);
        if (lane < 16) nAnp[wf * 128 + n] = p;
    }
    __syncthreads();
    if (t < 128) {
        float s = 0.f;
        #pragma unroll
        for (int w = 0; w < 8; ++w) s += nAnp[w * 128 + t];
        nAn_l[t] = s;
    }
    __syncthreads();
    int tx = t & 15, ty = t >> 4;                       // ty 0..31
    float pApk = pap[b * 16 + tx];
    float dp2  = dpos2[b * 16 + tx];
    float mn_a = __uint_as_float(0x7f800000u), mn_v = mn_a;
    #pragma unroll
    for (int ii = 0; ii < 4; ++ii) {
        int n = ty * 4 + ii;
        float d2v = pApk - 2.f * pAn_l[n * 17 + tx] + nAn_l[n];
        float cc = fmaxf(d2v, EPS_);
        mn_a = fminf(mn_a, cc);
        if (cc > dp2) mn_v = fminf(mn_v, cc);
    }
    reda[ty * 16 + tx] = mn_a; redv[ty * 16 + tx] = mn_v;
    __syncthreads();
    if (ty == 0) {
        float ra = reda[tx], rv = redv[tx];
        #pragma unroll
        for (int y = 1; y < 32; ++y) {
            ra = fminf(ra, reda[y * 16 + tx]);
            rv = fminf(rv, redv[y * 16 + tx]);
        }
        atomicMin(&mina[b * 16 + tx], __float_as_uint(ra));
        atomicMin(&minv[b * 16 + tx], __float_as_uint(rv));
    }
}

// ---------- final loss ----------
__global__ __launch_bounds__(256) void k5(const float* __restrict__ dpos2,
                                          const unsigned* __restrict__ mina,
                                          const unsigned* __restrict__ minv,
                                          float* __restrict__ out) {
    int t = threadIdx.x;
    __shared__ float red[256];
    float dp = sqrtf(dpos2[t]);
    unsigned mv = minv[t], ma = mina[t];
    unsigned sel = (mv < 0x7f800000u) ? mv : ma;
    float dn = sqrtf(__uint_as_float(sel));
    red[t] = fmaxf(dp - dn + ALPHA_, 0.f);
    __syncthreads();
    for (int s = 128; s > 0; s >>= 1) { if (t < s) red[t] += red[t + s]; __syncthreads(); }
    if (t == 0) out[0] = red[0] * (1.f / 256.f);
}

extern "C" void kernel_launch(void* const* d_in, const int* in_sizes, int n_in,
                              void* d_out, int out_size, void* d_ws, size_t ws_size,
                              hipStream_t stream) {
    (void)in_sizes; (void)n_in; (void)out_size; (void)ws_size;
    const float* Z1   = (const float*)d_in[0];
    const float* Z2   = (const float*)d_in[1];
    const int*   mat  = (const int*)d_in[2];
    const float* negs = (const float*)d_in[3];
    const float* Sig  = (const float*)d_in[4];
    float* ws = (float*)d_ws;
    unsigned short* S_H  = (unsigned short*)(ws + OFF_S_H);
    unsigned short* S_L  = (unsigned short*)(ws + OFF_S_L);
    unsigned short* XA_H = (unsigned short*)(ws + OFF_XA_H);
    unsigned short* XA_L = (unsigned short*)(ws + OFF_XA_L);
    unsigned short* XB_H = (unsigned short*)(ws + OFF_XB_H);
    unsigned short* XB_L = (unsigned short*)(ws + OFF_XB_L);
    unsigned short* T_H  = (unsigned short*)(ws + OFF_T_H);
    unsigned short* T_L  = (unsigned short*)(ws + OFF_T_L);
    unsigned short* PA_H = (unsigned short*)(ws + OFF_PA_H);
    unsigned short* PA_L = (unsigned short*)(ws + OFF_PA_L);
    unsigned short* NH   = (unsigned short*)(ws + OFF_NH);
    unsigned short* NL   = (unsigned short*)(ws + OFF_NL);
    unsigned* mina = (unsigned*)(ws + OFF_MINA);
    unsigned* minv = (unsigned*)(ws + OFF_MINV);
    float* out = (float*)d_out;

    kcolsum<<<256, 256, 0, stream>>>(Sig, ws + OFF_CS);
    kcoef<<<1, 256, 0, stream>>>(ws + OFF_CS, ws + OFF_C01);
    kinit<<<4096, 256, 0, stream>>>(Sig, ws, ws + OFF_C01);

    unsigned short* pah = XA_H; unsigned short* pal = XA_L;
    unsigned short* pbh = XB_H; unsigned short* pbl = XB_L;
    for (int it = 0; it < ITERS; ++it) {
        gemm_mfma<<<dim3(32, BB), 256, 0, stream>>>(S_H, S_L, pah, pal, T_H, T_L, 1);   // T = 2I - S@X
        gemm_mfma<<<dim3(32, BB), 256, 0, stream>>>(pah, pal, T_H, T_L, pbh, pbl, 0);   // X' = X@T
        unsigned short* th = pah; pah = pbh; pbh = th;
        unsigned short* tl = pal; pal = pbl; pbl = tl;
    }
    // ITERS=5 (odd) => final split inverse in XB_H/XB_L (== pah/pal); XA/T/S now dead

    knegsplit<<<NNEG * DD / 8 / 256, 256, 0, stream>>>(negs, NH, NL, mina, minv);
    k2<<<BB * KK, 256, 0, stream>>>(Z1, Z2, mat, pah, pal, ws);
    k3<<<BB * NNEG / 128, 512, 0, stream>>>(pah, pal, PA_H, PA_L, NH, NL,
                                            ws + OFF_PAP, ws + OFF_DPOS2, mina, minv);
    k5<<<1, 256, 0, stream>>>(ws + OFF_DPOS2, mina, minv, out);
}

// Round 8
// 380.638 us; speedup vs baseline: 1.6238x; 1.6238x over previous
//
#include <hip/hip_runtime.h>
#include <hip/hip_bf16.h>

#define ALPHA_ 0.2f
#define EPS_ 1e-12f

typedef short short8 __attribute__((ext_vector_type(8)));
typedef unsigned short ushort4v __attribute__((ext_vector_type(4)));
typedef float f32x4 __attribute__((ext_vector_type(4)));

constexpr int BB = 16, KK = 16, DD = 256, NNEG = 16384;
constexpr int ITERS = 5;   // Newton-Schulz iterations (odd => final lands in XB)

// ---- workspace layout (float offsets) ---- total 5,309,440 floats (proven size)
constexpr size_t OFF_NL    = 0;         // 2M floats: neg-lo (overlays XA after Newton)
constexpr size_t OFF_XA_H  = 1048576;
constexpr size_t OFF_XA_L  = 1572864;
constexpr size_t OFF_XB_H  = 2097152;   // FINAL A hi
constexpr size_t OFF_XB_L  = 2621440;   // FINAL A lo
constexpr size_t OFF_NH    = 3145728;   // 2M floats: neg-hi (overlays T+S after Newton)
constexpr size_t OFF_T_H   = 3145728;
constexpr size_t OFF_CS    = 3145728;   // colsum[16][256] (overlays T_H during prep)
constexpr size_t OFF_C01   = 3149824;   // c0[16], c1[16]
constexpr size_t OFF_T_L   = 3670016;
constexpr size_t OFF_S_H   = 4194304;
constexpr size_t OFF_S_L   = 4718592;
constexpr size_t OFF_PA_H  = 5242880;   // 65536 ushorts
constexpr size_t OFF_PA_L  = 5275648;
constexpr size_t OFF_PAP   = 5308416;
constexpr size_t OFF_DPOS2 = 5308672;
constexpr size_t OFF_MINA  = 5308928;
constexpr size_t OFF_MINV  = 5309184;

// ---------- bf16 split helpers (RNE) ----------
__device__ inline unsigned short bf_hi(float x) {
    unsigned u = __float_as_uint(x);
    return (unsigned short)((u + 0x7fffu + ((u >> 16) & 1u)) >> 16);
}
__device__ inline float bf_tof(unsigned short h) { return __uint_as_float(((unsigned)h) << 16); }
__device__ inline void split2(float x, unsigned short& h, unsigned short& l) {
    h = bf_hi(x); l = bf_hi(x - bf_tof(h));
}

// ---------- prep 1: column abs-sums (Gershgorin), 256 blocks ----------
__global__ __launch_bounds__(256) void kcolsum(const float* __restrict__ Sig, float* __restrict__ cs) {
    int b = blockIdx.x >> 4, cg = blockIdx.x & 15;
    int t = threadIdx.x, tx = t & 15, rg = t >> 4;
    const float* S = Sig + (size_t)b * 65536;
    int col = cg * 16 + tx;
    float s = 0.f;
    #pragma unroll 4
    for (int i = rg * 16; i < rg * 16 + 16; ++i) s += fabsf(S[(size_t)i * 256 + col]);
    __shared__ float red[256];
    red[rg * 16 + tx] = s; __syncthreads();
    if (rg == 0) {
        float tot = 0.f;
        #pragma unroll
        for (int y = 0; y < 16; ++y) tot += red[y * 16 + tx];
        cs[b * 256 + col] = tot;
    }
}

// ---------- prep 2: G = max colsum -> degree-2 init coefficients ----------
__global__ __launch_bounds__(256) void kcoef(const float* __restrict__ cs, float* __restrict__ c01) {
    int t = threadIdx.x, b = t >> 4, ch = t & 15;
    float m = 0.f;
    #pragma unroll
    for (int i = 0; i < 16; ++i) m = fmaxf(m, cs[b * 256 + ch * 16 + i]);
    __shared__ float red[256];
    red[t] = m; __syncthreads();
    if (ch == 0) {
        float G = red[b * 16];
        #pragma unroll
        for (int y = 1; y < 16; ++y) G = fmaxf(G, red[b * 16 + y]);
        float c1 = -2.f / (G + (G + 1.f) * (G + 1.f) * 0.25f);
        c01[b] = -c1 * (G + 1.f); c01[16 + b] = c1;
    }
}

// ---------- prep 3: split S and X0 = c0*I + c1*S (4096 blocks, coalesced) ----------
__global__ __launch_bounds__(256) void kinit(const float* __restrict__ Sig, float* __restrict__ ws,
                                             const float* __restrict__ c01) {
    int idx = blockIdx.x * 256 + threadIdx.x;
    int b = idx >> 16, rc = idx & 65535;
    int r = rc >> 8, c = rc & 255;
    float v = Sig[idx];
    unsigned short h, l;
    split2(v, h, l);
    ((unsigned short*)(ws + OFF_S_H))[idx] = h; ((unsigned short*)(ws + OFF_S_L))[idx] = l;
    float x0 = c01[16 + b] * v + ((r == c) ? c01[b] : 0.f);
    split2(x0, h, l);
    ((unsigned short*)(ws + OFF_XA_H))[idx] = h; ((unsigned short*)(ws + OFF_XA_L))[idx] = l;
}

// ---------- batched 256x256 MFMA split GEMM, 32x64 tiles, XCD-local b mapping ----------
__global__ __launch_bounds__(256) void gemm_mfma(const unsigned short* __restrict__ Ah,
                                                 const unsigned short* __restrict__ Al,
                                                 const unsigned short* __restrict__ Bh,
                                                 const unsigned short* __restrict__ Bl,
                                                 unsigned short* __restrict__ Ch,
                                                 unsigned short* __restrict__ Cl, int mode2i) {
    int lin = blockIdx.x;
    int x = lin & 7, q = lin >> 3;                  // XCD x owns b in {2x, 2x+1}
    int b = x * 2 + (q >> 5);
    int tile = q & 31;
    int i0 = (tile >> 2) * 32, j0 = (tile & 3) * 64;
    size_t base = (size_t)b * 65536;
    int t = threadIdx.x, lane = t & 63, w = t >> 6;
    int l15 = lane & 15, lg = lane >> 4;
    f32x4 acc[2] = {};
    int ar0 = i0 + l15;
    int br  = j0 + w * 16 + l15;
    #pragma unroll
    for (int e0 = 0; e0 < 256; e0 += 32) {
        int eo = e0 + 8 * lg;
        short8 a_h[2], a_l[2];
        #pragma unroll
        for (int m = 0; m < 2; ++m) {
            size_t off = base + (size_t)(ar0 + m * 16) * 256 + eo;
            a_h[m] = *reinterpret_cast<const short8*>(Ah + off);
            a_l[m] = *reinterpret_cast<const short8*>(Al + off);
        }
        size_t boff = base + (size_t)br * 256 + eo;     // symmetric: row == col
        short8 b_h = *reinterpret_cast<const short8*>(Bh + boff);
        short8 b_l = *reinterpret_cast<const short8*>(Bl + boff);
        #pragma unroll
        for (int m = 0; m < 2; ++m) {
            acc[m] = __builtin_amdgcn_mfma_f32_16x16x32_bf16(a_h[m], b_h, acc[m], 0, 0, 0);
            acc[m] = __builtin_amdgcn_mfma_f32_16x16x32_bf16(a_h[m], b_l, acc[m], 0, 0, 0);
            acc[m] = __builtin_amdgcn_mfma_f32_16x16x32_bf16(a_l[m], b_h, acc[m], 0, 0, 0);
        }
    }
    #pragma unroll
    for (int m = 0; m < 2; ++m)
        #pragma unroll
        for (int r = 0; r < 4; ++r) {
            int row = i0 + m * 16 + 4 * lg + r;
            int col = j0 + w * 16 + l15;
            float v = acc[m][r];
            if (mode2i) v = ((row == col) ? 2.f : 0.f) - v;
            unsigned short h, l; split2(v, h, l);
            size_t off = base + (size_t)row * 256 + col;
            Ch[off] = h; Cl[off] = l;
        }
}

// ---------- negatives pre-split (once) + min-buffer init ----------
__global__ __launch_bounds__(256) void knegsplit(const float* __restrict__ negs,
                                                 unsigned short* __restrict__ NH,
                                                 unsigned short* __restrict__ NL,
                                                 unsigned* __restrict__ mina,
                                                 unsigned* __restrict__ minv) {
    size_t i8 = ((size_t)blockIdx.x * 256 + threadIdx.x) * 8;
    f32x4 v0 = *reinterpret_cast<const f32x4*>(negs + i8);
    f32x4 v1 = *reinterpret_cast<const f32x4*>(negs + i8 + 4);
    short8 h, l;
    #pragma unroll
    for (int j = 0; j < 4; ++j) {
        unsigned short hh, ll;
        split2(v0[j], hh, ll); h[j] = (short)hh; l[j] = (short)ll;
        split2(v1[j], hh, ll); h[4 + j] = (short)hh; l[4 + j] = (short)ll;
    }
    *reinterpret_cast<short8*>(NH + i8) = h;
    *reinterpret_cast<short8*>(NL + i8) = l;
    if (blockIdx.x == 0) {
        mina[threadIdx.x] = 0x7f800000u; minv[threadIdx.x] = 0x7f800000u;
    }
}

// ---------- per (b,k): PA row (split), pAp, dpos2 ----------
__global__ __launch_bounds__(256) void k2(const float* __restrict__ Z1, const float* __restrict__ Z2,
                                          const int* __restrict__ match,
                                          const unsigned short* __restrict__ AH,
                                          const unsigned short* __restrict__ AL,
                                          float* __restrict__ ws) {
    int bk = blockIdx.x; int b = bk >> 4; int t = threadIdx.x;
    const unsigned short* Ah = AH + (size_t)b * 65536;
    const unsigned short* Al = AL + (size_t)b * 65536;
    __shared__ float z[DD], df[DD];
    __shared__ float red[256];
    int m = match[bk];
    float zv = Z1[(size_t)bk * DD + t];
    float qv = Z2[((size_t)b * KK + m) * DD + t];
    z[t] = zv; df[t] = zv - qv;
    __syncthreads();
    float pa = 0.f, da = 0.f;
    for (int e = 0; e < DD; ++e) {
        float Ae = bf_tof(Ah[(size_t)e * 256 + t]) + bf_tof(Al[(size_t)e * 256 + t]);
        pa = fmaf(z[e], Ae, pa);
        da = fmaf(df[e], Ae, da);
    }
    unsigned short ph, pl; split2(pa, ph, pl);
    ((unsigned short*)(ws + OFF_PA_H))[(size_t)bk * 256 + t] = ph;
    ((unsigned short*)(ws + OFF_PA_L))[(size_t)bk * 256 + t] = pl;
    float dfv = df[t];
    red[t] = pa * zv; __syncthreads();
    for (int s = 128; s > 0; s >>= 1) { if (t < s) red[t] += red[t + s]; __syncthreads(); }
    float pAp = red[0]; __syncthreads();
    red[t] = da * dfv; __syncthreads();
    for (int s = 128; s > 0; s >>= 1) { if (t < s) red[t] += red[t + s]; __syncthreads(); }
    if (t == 0) {
        ws[OFF_PAP + bk]   = pAp;
        ws[OFF_DPOS2 + bk] = fmaxf(red[0], EPS_);
    }
}

// ---------- main kernel: role-swapped, LDS dbuf negatives, 1 barrier/chunk ----------
// 512 thr = 8 waves. Wave wf: f-tiles {wf, wf+8}, all 8 n-subtiles (j-outer, LDS read once).
// PA tile: wf0 handles j0-3, wf1 j4-7. launch_bounds(512,2): 256-reg cap, NO spill.
__global__ __launch_bounds__(512, 2) void k3(const unsigned short* __restrict__ Ahi,
                                             const unsigned short* __restrict__ Alo,
                                             const unsigned short* __restrict__ PAh,
                                             const unsigned short* __restrict__ PAl,
                                             const unsigned short* __restrict__ NH,
                                             const unsigned short* __restrict__ NL,
                                             const float* __restrict__ pap,
                                             const float* __restrict__ dpos2,
                                             unsigned* __restrict__ mina,
                                             unsigned* __restrict__ minv) {
    __shared__ float smem[10240];                      // 40 KB: 2 x dbuf [128][40] x {h,l}
    unsigned short* BH0 = (unsigned short*)smem;
    unsigned short* BL0 = BH0 + 5120;
    unsigned short* BH1 = BL0 + 5120;
    unsigned short* BL1 = BH1 + 5120;

    int lin = blockIdx.x;
    int x  = lin & 7;
    int q  = lin >> 3;
    int b  = q >> 4;
    int n0 = (x * 16 + (q & 15)) * 128;                // XCD-local negative slice
    int t = threadIdx.x, lane = t & 63, wf = t >> 6;
    int l15 = lane & 15, lg = lane >> 4;
    const unsigned short* Ab  = Ahi + (size_t)b * 65536;
    const unsigned short* Al_ = Alo + (size_t)b * 65536;
    const unsigned short* Ph  = PAh + (size_t)b * 4096;
    const unsigned short* Pl  = PAl + (size_t)b * 4096;
    const unsigned short* Nh  = NH + (size_t)n0 * 256;
    const unsigned short* Nl  = NL + (size_t)n0 * 256;

    int srow = t >> 2, sq = t & 3;                     // staging: neg row, 16B quarter
    const unsigned short* NhS = Nh + (size_t)srow * 256 + sq * 8;
    const unsigned short* NlS = Nl + (size_t)srow * 256 + sq * 8;
    int soff = srow * 40 + sq * 8;

    // A-row fragment base pointers (fixed per thread; e-window advances by c*32)
    const unsigned short* a0h = Ab  + (size_t)(wf * 16 + l15) * 256 + 8 * lg;
    const unsigned short* a0l = Al_ + (size_t)(wf * 16 + l15) * 256 + 8 * lg;
    const unsigned short* a1h = Ab  + (size_t)((wf + 8) * 16 + l15) * 256 + 8 * lg;
    const unsigned short* a1l = Al_ + (size_t)((wf + 8) * 16 + l15) * 256 + 8 * lg;
    const unsigned short* pph = Ph + (size_t)l15 * 256 + 8 * lg;
    const unsigned short* ppl = Pl + (size_t)l15 * 256 + 8 * lg;

    f32x4 acc[2][8] = {};
    f32x4 accp[4] = {};

    // prologue: stage chunk 0 into buf0
    short8 sH = *reinterpret_cast<const short8*>(NhS);
    short8 sL = *reinterpret_cast<const short8*>(NlS);
    *reinterpret_cast<short8*>(BH0 + soff) = sH;
    *reinterpret_cast<short8*>(BL0 + soff) = sL;
    __syncthreads();

    #pragma unroll
    for (int c = 0; c < 8; ++c) {
        unsigned short* cH = (c & 1) ? BH1 : BH0;
        unsigned short* cL = (c & 1) ? BL1 : BL0;
        unsigned short* nH = (c & 1) ? BH0 : BH1;
        unsigned short* nL = (c & 1) ? BL0 : BL1;
        if (c < 7) {                                    // stage loads for c+1 (early issue)
            sH = *reinterpret_cast<const short8*>(NhS + (c + 1) * 32);
            sL = *reinterpret_cast<const short8*>(NlS + (c + 1) * 32);
        }
        // a-frags for this chunk (global, L2-hot)
        short8 a0h_ = *reinterpret_cast<const short8*>(a0h + c * 32);
        short8 a0l_ = *reinterpret_cast<const short8*>(a0l + c * 32);
        short8 a1h_ = *reinterpret_cast<const short8*>(a1h + c * 32);
        short8 a1l_ = *reinterpret_cast<const short8*>(a1l + c * 32);
        short8 ph_, pl_;
        if (wf < 2) {
            ph_ = *reinterpret_cast<const short8*>(pph + c * 32);
            pl_ = *reinterpret_cast<const short8*>(ppl + c * 32);
        }
        #pragma unroll
        for (int j = 0; j < 8; ++j) {                   // j-outer: LDS read ONCE per j
            short8 bh = *reinterpret_cast<const short8*>(cH + (j * 16 + l15) * 40 + 8 * lg);
            short8 bl = *reinterpret_cast<const short8*>(cL + (j * 16 + l15) * 40 + 8 * lg);
            acc[0][j] = __builtin_amdgcn_mfma_f32_16x16x32_bf16(a0h_, bh, acc[0][j], 0, 0, 0);
            acc[0][j] = __builtin_amdgcn_mfma_f32_16x16x32_bf16(a0h_, bl, acc[0][j], 0, 0, 0);
            acc[0][j] = __builtin_amdgcn_mfma_f32_16x16x32_bf16(a0l_, bh, acc[0][j], 0, 0, 0);
            acc[1][j] = __builtin_amdgcn_mfma_f32_16x16x32_bf16(a1h_, bh, acc[1][j], 0, 0, 0);
            acc[1][j] = __builtin_amdgcn_mfma_f32_16x16x32_bf16(a1h_, bl, acc[1][j], 0, 0, 0);
            acc[1][j] = __builtin_amdgcn_mfma_f32_16x16x32_bf16(a1l_, bh, acc[1][j], 0, 0, 0);
            if (wf < 2 && (j >> 2) == wf) {
                const int jj = j & 3;
                accp[jj] = __builtin_amdgcn_mfma_f32_16x16x32_bf16(ph_, bh, accp[jj], 0, 0, 0);
                accp[jj] = __builtin_amdgcn_mfma_f32_16x16x32_bf16(ph_, bl, accp[jj], 0, 0, 0);
                accp[jj] = __builtin_amdgcn_mfma_f32_16x16x32_bf16(pl_, bh, accp[jj], 0, 0, 0);
            }
        }
        if (c < 7) {                                    // write next buffer (distinct from cur)
            *reinterpret_cast<short8*>(nH + soff) = sH;
            *reinterpret_cast<short8*>(nL + soff) = sL;
        }
        __syncthreads();                                // single barrier per chunk
    }

    // ---- epilogue (smem reused; last barrier above fences the dbuf reads) ----
    float* pAn_l = smem;            // [128][17]
    float* nAnp  = smem + 2176;     // [8][128]
    float* nAn_l = smem + 3200;     // [128]
    float* reda  = smem + 3328;     // [512]
    float* redv  = smem + 3840;     // [512]

    if (wf < 2) {
        #pragma unroll
        for (int jj = 0; jj < 4; ++jj) {
            int n = (wf * 4 + jj) * 16 + l15;
            #pragma unroll
            for (int r = 0; r < 4; ++r)
                pAn_l[n * 17 + 4 * lg + r] = accp[jj][r];   // pAn[n][k], k=4lg+r
        }
    }
    #pragma unroll
    for (int j = 0; j < 8; ++j) {
        int n = j * 16 + l15;
        float p = 0.f;
        #pragma unroll
        for (int i = 0; i < 2; ++i) {
            int fb = (wf + 8 * i) * 16 + 4 * lg;
            ushort4v wh = *reinterpret_cast<const ushort4v*>(NH + (size_t)(n0 + n) * 256 + fb);
            ushort4v wl = *reinterpret_cast<const ushort4v*>(NL + (size_t)(n0 + n) * 256 + fb);
            #pragma unroll
            for (int r = 0; r < 4; ++r) {
                float w = bf_tof(wh[r]) + bf_tof(wl[r]);
                p = fmaf(acc[i][j][r], w, p);
            }
        }
        p += __shfl_xor(p, 16);                         // reduce over lg (f-rows)
        p += __shfl_xor(p, 32);
        if (lane < 16) nAnp[wf * 128 + n] = p;
    }
    __syncthreads();
    if (t < 128) {
        float s = 0.f;
        #pragma unroll
        for (int w = 0; w < 8; ++w) s += nAnp[w * 128 + t];
        nAn_l[t] = s;
    }
    __syncthreads();
    int tx = t & 15, ty = t >> 4;                       // ty 0..31
    float pApk = pap[b * 16 + tx];
    float dp2  = dpos2[b * 16 + tx];
    float mn_a = __uint_as_float(0x7f800000u), mn_v = mn_a;
    #pragma unroll
    for (int ii = 0; ii < 4; ++ii) {
        int n = ty * 4 + ii;
        float d2v = pApk - 2.f * pAn_l[n * 17 + tx] + nAn_l[n];
        float cc = fmaxf(d2v, EPS_);
        mn_a = fminf(mn_a, cc);
        if (cc > dp2) mn_v = fminf(mn_v, cc);
    }
    reda[ty * 16 + tx] = mn_a; redv[ty * 16 + tx] = mn_v;
    __syncthreads();
    if (ty == 0) {
        float ra = reda[tx], rv = redv[tx];
        #pragma unroll
        for (int y = 1; y < 32; ++y) {
            ra = fminf(ra, reda[y * 16 + tx]);
            rv = fminf(rv, redv[y * 16 + tx]);
        }
        atomicMin(&mina[b * 16 + tx], __float_as_uint(ra));
        atomicMin(&minv[b * 16 + tx], __float_as_uint(rv));
    }
}

// ---------- final loss ----------
__global__ __launch_bounds__(256) void k5(const float* __restrict__ dpos2,
                                          const unsigned* __restrict__ mina,
                                          const unsigned* __restrict__ minv,
                                          float* __restrict__ out) {
    int t = threadIdx.x;
    __shared__ float red[256];
    float dp = sqrtf(dpos2[t]);
    unsigned mv = minv[t], ma = mina[t];
    unsigned sel = (mv < 0x7f800000u) ? mv : ma;
    float dn = sqrtf(__uint_as_float(sel));
    red[t] = fmaxf(dp - dn + ALPHA_, 0.f);
    __syncthreads();
    for (int s = 128; s > 0; s >>= 1) { if (t < s) red[t] += red[t + s]; __syncthreads(); }
    if (t == 0) out[0] = red[0] * (1.f / 256.f);
}

extern "C" void kernel_launch(void* const* d_in, const int* in_sizes, int n_in,
                              void* d_out, int out_size, void* d_ws, size_t ws_size,
                              hipStream_t stream) {
    (void)in_sizes; (void)n_in; (void)out_size; (void)ws_size;
    const float* Z1   = (const float*)d_in[0];
    const float* Z2   = (const float*)d_in[1];
    const int*   mat  = (const int*)d_in[2];
    const float* negs = (const float*)d_in[3];
    const float* Sig  = (const float*)d_in[4];
    float* ws = (float*)d_ws;
    unsigned short* S_H  = (unsigned short*)(ws + OFF_S_H);
    unsigned short* S_L  = (unsigned short*)(ws + OFF_S_L);
    unsigned short* XA_H = (unsigned short*)(ws + OFF_XA_H);
    unsigned short* XA_L = (unsigned short*)(ws + OFF_XA_L);
    unsigned short* XB_H = (unsigned short*)(ws + OFF_XB_H);
    unsigned short* XB_L = (unsigned short*)(ws + OFF_XB_L);
    unsigned short* T_H  = (unsigned short*)(ws + OFF_T_H);
    unsigned short* T_L  = (unsigned short*)(ws + OFF_T_L);
    unsigned short* PA_H = (unsigned short*)(ws + OFF_PA_H);
    unsigned short* PA_L = (unsigned short*)(ws + OFF_PA_L);
    unsigned short* NH   = (unsigned short*)(ws + OFF_NH);
    unsigned short* NL   = (unsigned short*)(ws + OFF_NL);
    unsigned* mina = (unsigned*)(ws + OFF_MINA);
    unsigned* minv = (unsigned*)(ws + OFF_MINV);
    float* out = (float*)d_out;

    kcolsum<<<256, 256, 0, stream>>>(Sig, ws + OFF_CS);
    kcoef<<<1, 256, 0, stream>>>(ws + OFF_CS, ws + OFF_C01);
    kinit<<<4096, 256, 0, stream>>>(Sig, ws, ws + OFF_C01);

    unsigned short* pah = XA_H; unsigned short* pal = XA_L;
    unsigned short* pbh = XB_H; unsigned short* pbl = XB_L;
    for (int it = 0; it < ITERS; ++it) {
        gemm_mfma<<<512, 256, 0, stream>>>(S_H, S_L, pah, pal, T_H, T_L, 1);   // T = 2I - S@X
        gemm_mfma<<<512, 256, 0, stream>>>(pah, pal, T_H, T_L, pbh, pbl, 0);   // X' = X@T
        unsigned short* th = pah; pah = pbh; pbh = th;
        unsigned short* tl = pal; pal = pbl; pbl = tl;
    }
    // ITERS=5 (odd) => final split inverse in XB_H/XB_L (== pah/pal); XA/T/S now dead

    knegsplit<<<NNEG * DD / 8 / 256, 256, 0, stream>>>(negs, NH, NL, mina, minv);
    k2<<<BB * KK, 256, 0, stream>>>(Z1, Z2, mat, pah, pal, ws);
    k3<<<BB * NNEG / 128, 512, 0, stream>>>(pah, pal, PA_H, PA_L, NH, NL,
                                            ws + OFF_PAP, ws + OFF_DPOS2, mina, minv);
    k5<<<1, 256, 0, stream>>>(ws + OFF_DPOS2, mina, minv, out);
}